// Round 5
// baseline (276.001 us; speedup 1.0000x reference)
//
#include <hip/hip_runtime.h>

// Skewed MAE: mean(|p - t| * exp(sign(t - p) * (2t - 1)))
// (Both lambda ramps collapse to lam(t) = 2t-1.)
//
// R3: no-atomic stage1 stuck at 100us / 2.68 TB/s delivered, VGPR=12,
// VALUBusy 8% -- compiler keeps the loop at 2-loads-then-vmcnt(0).
// R4: tied "+v" struct operands don't codegen on gfx950.
// R5: single asm block = 8x global_load_dwordx4 + s_waitcnt vmcnt(0),
// loaded values are the asm OUTPUTS (early-clobber), so consumers
// data-depend on the post-waitcnt block. 8 KB in flight per wave.

#define BLOCK 256
#define GRID 2048

__device__ __forceinline__ float skew_elem(float p, float t) {
    float d = p - t;
    float lam = __builtin_fmaf(2.0f, t, -1.0f);     // 2t - 1
    float s = (d < 0.0f) ? lam : -lam;              // sign(t-p)*lam; d==0 -> |d|=0
    return fabsf(d) * __expf(s);
}

__device__ __forceinline__ float block_reduce(float acc) {
    #pragma unroll
    for (int off = 32; off > 0; off >>= 1)
        acc += __shfl_down(acc, off, 64);
    __shared__ float smem[BLOCK / 64];
    int lane = threadIdx.x & 63;
    int wave = threadIdx.x >> 6;
    if (lane == 0) smem[wave] = acc;
    __syncthreads();
    float s = 0.0f;
    #pragma unroll
    for (int w = 0; w < BLOCK / 64; ++w) s += smem[w];
    return s;
}

__global__ __launch_bounds__(BLOCK) void skewed_mae_stage1(
        const float4* __restrict__ yp4, const float4* __restrict__ yt4,
        const float* __restrict__ yp, const float* __restrict__ yt,
        float* __restrict__ partials, int n4, int n, float inv_n) {
    const int tid = blockIdx.x * BLOCK + threadIdx.x;
    const int stride = GRID * BLOCK;

    float acc = 0.0f;

    int base = tid;
    for (; base + 3 * stride < n4; base += 4 * stride) {
        float4 p0, p1, p2, p3, t0, t1, t2, t3;
        // 8 loads issued back-to-back, one drain; values are asm outputs so
        // no consumer can execute before the s_waitcnt.
        asm volatile(
            "global_load_dwordx4 %0, %8, off\n\t"
            "global_load_dwordx4 %1, %9, off\n\t"
            "global_load_dwordx4 %2, %10, off\n\t"
            "global_load_dwordx4 %3, %11, off\n\t"
            "global_load_dwordx4 %4, %12, off\n\t"
            "global_load_dwordx4 %5, %13, off\n\t"
            "global_load_dwordx4 %6, %14, off\n\t"
            "global_load_dwordx4 %7, %15, off\n\t"
            "s_waitcnt vmcnt(0)"
            : "=&v"(p0), "=&v"(p1), "=&v"(p2), "=&v"(p3),
              "=&v"(t0), "=&v"(t1), "=&v"(t2), "=&v"(t3)
            : "v"(yp4 + base),              "v"(yp4 + base + stride),
              "v"(yp4 + base + 2 * stride), "v"(yp4 + base + 3 * stride),
              "v"(yt4 + base),              "v"(yt4 + base + stride),
              "v"(yt4 + base + 2 * stride), "v"(yt4 + base + 3 * stride));

        acc += skew_elem(p0.x, t0.x); acc += skew_elem(p0.y, t0.y);
        acc += skew_elem(p0.z, t0.z); acc += skew_elem(p0.w, t0.w);
        acc += skew_elem(p1.x, t1.x); acc += skew_elem(p1.y, t1.y);
        acc += skew_elem(p1.z, t1.z); acc += skew_elem(p1.w, t1.w);
        acc += skew_elem(p2.x, t2.x); acc += skew_elem(p2.y, t2.y);
        acc += skew_elem(p2.z, t2.z); acc += skew_elem(p2.w, t2.w);
        acc += skew_elem(p3.x, t3.x); acc += skew_elem(p3.y, t3.y);
        acc += skew_elem(p3.z, t3.z); acc += skew_elem(p3.w, t3.w);
    }
    // Remainder float4 chunks (normal loads; asm queue drained above).
    for (; base < n4; base += stride) {
        float4 p = yp4[base];
        float4 t = yt4[base];
        acc += skew_elem(p.x, t.x);
        acc += skew_elem(p.y, t.y);
        acc += skew_elem(p.z, t.z);
        acc += skew_elem(p.w, t.w);
    }
    // Scalar tail (empty for n = 33554432).
    for (int i = n4 * 4 + tid; i < n; i += stride) {
        acc += skew_elem(yp[i], yt[i]);
    }
    acc *= inv_n;

    float s = block_reduce(acc);
    if (threadIdx.x == 0) partials[blockIdx.x] = s;
}

// Stage 2: one block reduces GRID partials and writes the scalar output.
__global__ __launch_bounds__(BLOCK) void skewed_mae_stage2(
        const float* __restrict__ partials, float* __restrict__ out) {
    float acc = 0.0f;
    #pragma unroll
    for (int k = 0; k < GRID / BLOCK; ++k)
        acc += partials[k * BLOCK + threadIdx.x];
    float s = block_reduce(acc);
    if (threadIdx.x == 0) out[0] = s;
}

extern "C" void kernel_launch(void* const* d_in, const int* in_sizes, int n_in,
                              void* d_out, int out_size, void* d_ws, size_t ws_size,
                              hipStream_t stream) {
    const float* yp = (const float*)d_in[0];
    const float* yt = (const float*)d_in[1];
    float* out = (float*)d_out;
    float* partials = (float*)d_ws;    // GRID floats = 8 KB scratch
    int n = in_sizes[0];
    int n4 = n / 4;

    skewed_mae_stage1<<<GRID, BLOCK, 0, stream>>>(
        (const float4*)yp, (const float4*)yt, yp, yt, partials, n4, n,
        1.0f / (float)n);
    skewed_mae_stage2<<<1, BLOCK, 0, stream>>>(partials, out);
}